// Round 11
// baseline (21.535 us; speedup 1.0000x reference)
//
#include <hip/hip_runtime.h>

// Fused NeRF: PE (4 freq) + MLP 27->32->1, both layers bf16 MFMA.
// R10: sin/cos via 4096-entry LDS table (2 ds_read) instead of v_sin/v_cos
// (trans pipe ~16-32 cyc/wave64 op was ~60-80% of the inner loop per R8 diag).
// Table err <= 2pi/4096 ~ 1.5e-3 rad, negligible vs 5.2e-2 threshold.

#define NPTS  2097152
#define BLOCK 256
#define TILES 4
#define NBLK  (NPTS / (BLOCK * TILES))   // 2048
#define TABN  4096

typedef __bf16 bf16x8 __attribute__((ext_vector_type(8)));
typedef float  f32x8  __attribute__((ext_vector_type(8)));
typedef float  f32x4  __attribute__((ext_vector_type(4)));

__global__ __launch_bounds__(BLOCK, 8) void nerf_tab(
    const float* __restrict__ x,
    const float* __restrict__ W1,
    const float* __restrict__ b1,
    const float* __restrict__ W2,
    const float* __restrict__ b2,
    float* __restrict__ out)
{
    __shared__ float stab[TABN];   // sin(2*pi*i/TABN), 16 KB

    const int tid  = threadIdx.x;
    const int wave = tid >> 6;
    const int lane = tid & 63;
    const int g    = lane >> 4;   // K-group: this lane's frequency band
    const int c    = lane & 15;   // col-within-16 (point low bits / j-row)

    // ---- build sin table (16 trans/thread, once per block) ----
    #pragma unroll
    for (int i = 0; i < TABN / BLOCK; ++i) {
        const int idx = tid + i * BLOCK;
        stab[idx] = __builtin_amdgcn_sinf((float)idx * (1.0f / TABN));
    }

    // ---- weight gathers issued while table trans ops complete ----
    const float INV2PI = 0.15915494309189535f;
    float Fg = 1.0f;
    Fg = (g == 1) ? 10.079368f : Fg;
    Fg = (g == 2) ? 101.59367f : Fg;
    Fg = (g == 3) ? 1024.0f    : Fg;
    const float FgN = Fg * INV2PI * (float)TABN;   // x -> table index scale

    bf16x8 afrag[2];
    #pragma unroll
    for (int mt = 0; mt < 2; ++mt) {
        const int j = mt * 16 + c;
        f32x8 af;
        #pragma unroll
        for (int i = 0; i < 3; ++i) af[i] = W1[(3 + 6 * g + i) * 32 + j];
        #pragma unroll
        for (int i = 3; i < 6; ++i) af[i] = W1[(6 + 6 * g + (i - 3)) * 32 + j];
        af[6] = (g < 3) ? W1[g * 32 + j] : b1[j];
        af[7] = 0.0f;
        afrag[mt] = __builtin_convertvector(af, bf16x8);
    }
    bf16x8 a2;
    {
        f32x8 a2f;
        #pragma unroll
        for (int i = 0; i < 4; ++i) {
            a2f[i]     = W2[4 * g + i];
            a2f[4 + i] = W2[16 + 4 * g + i];
        }
        a2 = __builtin_convertvector(a2f, bf16x8);
    }
    const float bias2 = b2[0];
    const f32x4 Z = {0.f, 0.f, 0.f, 0.f};   // pinned zero C-operand

    __syncthreads();

    const int tbase = blockIdx.x * (4 * TILES) + wave * TILES;

    #pragma unroll
    for (int t = 0; t < TILES; ++t) {
        const float3* xb3 = (const float3*)(x + (size_t)(tbase + t) * 192);
        float3 P[4];
        #pragma unroll
        for (int nt = 0; nt < 4; ++nt) P[nt] = xb3[16 * nt + c];

        float p[4];
        #pragma unroll
        for (int nt = 0; nt < 4; ++nt) {
            const float x0 = P[nt].x, x1 = P[nt].y, x2 = P[nt].z;

            // table-based sincos at this lane's band
            const int i0 = (int)(x0 * FgN);
            const int i1 = (int)(x1 * FgN);
            const int i2 = (int)(x2 * FgN);

            float extra = x0;
            extra = (g == 1) ? x1 : extra;
            extra = (g == 2) ? x2 : extra;
            extra = (g == 3) ? 1.0f : extra;

            f32x8 bff;
            bff[0] = stab[i0 & (TABN - 1)];
            bff[1] = stab[i1 & (TABN - 1)];
            bff[2] = stab[i2 & (TABN - 1)];
            bff[3] = stab[(i0 + TABN / 4) & (TABN - 1)];
            bff[4] = stab[(i1 + TABN / 4) & (TABN - 1)];
            bff[5] = stab[(i2 + TABN / 4) & (TABN - 1)];
            bff[6] = extra;
            bff[7] = 0.0f;
            const bf16x8 bf = __builtin_convertvector(bff, bf16x8);

            // layer 1: 2 MFMAs -> lane holds h[4g+r], h[16+4g+r]
            const f32x4 acc0 =
                __builtin_amdgcn_mfma_f32_16x16x32_bf16(afrag[0], bf, Z, 0, 0, 0);
            const f32x4 acc1 =
                __builtin_amdgcn_mfma_f32_16x16x32_bf16(afrag[1], bf, Z, 0, 0, 0);

            // layer 2: relu -> bf16 -> one MFMA; answer in o[0]
            f32x8 hf;
            #pragma unroll
            for (int r = 0; r < 4; ++r) {
                hf[r]     = fmaxf(acc0[r], 0.0f);
                hf[4 + r] = fmaxf(acc1[r], 0.0f);
            }
            const bf16x8 h8 = __builtin_convertvector(hf, bf16x8);
            const f32x4 o =
                __builtin_amdgcn_mfma_f32_16x16x32_bf16(a2, h8, Z, 0, 0, 0);
            p[nt] = o[0];
        }

        float v = p[0];
        v = (g == 1) ? p[1] : v;
        v = (g == 2) ? p[2] : v;
        v = (g == 3) ? p[3] : v;
        out[(size_t)(tbase + t) * 64 + lane] = fmaxf(v + bias2, 0.0f);
    }
}

extern "C" void kernel_launch(void* const* d_in, const int* in_sizes, int n_in,
                              void* d_out, int out_size, void* d_ws, size_t ws_size,
                              hipStream_t stream) {
    const float* x  = (const float*)d_in[0];
    const float* W1 = (const float*)d_in[1];
    const float* b1 = (const float*)d_in[2];
    const float* W2 = (const float*)d_in[3];
    const float* b2 = (const float*)d_in[4];
    float* out = (float*)d_out;

    nerf_tab<<<NBLK, BLOCK, 0, stream>>>(x, W1, b1, W2, b2, out);
}

// Round 12
// 19.978 us; speedup vs baseline: 1.0779x; 1.0779x over previous
//
#include <hip/hip_runtime.h>

// Fused NeRF: PE (4 freq) + MLP 27->32->1, both layers bf16 MFMA.
// R11: (a) 4096-entry PACKED bf16 {sin,cos} LDS table -> per angle one
// ds_read_b32 replaces v_sin+v_cos+fract AND the bf16 packing (k-order
// interleaved [s0,c0,s1,c1,s2,c2,extra,0]; W1-row permutation absorbs it).
// (b) W1/b1/W2 staged into LDS via 232 coalesced float4 loads; per-lane
// fragment gathers hit LDS instead of ~35 scattered global loads.

#define NPTS  2097152
#define BLOCK 256
#define TILES 4
#define NBLK  (NPTS / (BLOCK * TILES))   // 2048
#define TABN  4096

typedef __bf16 bf16x8 __attribute__((ext_vector_type(8)));
typedef __bf16 bf16x2 __attribute__((ext_vector_type(2)));
typedef float  f32x8  __attribute__((ext_vector_type(8)));
typedef float  f32x4  __attribute__((ext_vector_type(4)));
typedef float  f32x2  __attribute__((ext_vector_type(2)));
typedef unsigned int u32;
typedef u32 u32x4 __attribute__((ext_vector_type(4)));

__global__ __launch_bounds__(BLOCK, 4) void nerf_ptab(
    const float* __restrict__ x,
    const float* __restrict__ W1,
    const float* __restrict__ b1,
    const float* __restrict__ W2,
    const float* __restrict__ b2,
    float* __restrict__ out)
{
    __shared__ u32 stab[TABN];                 // {bf16 sin | bf16 cos<<16}
    __shared__ __align__(16) float ws[928];    // W1 (864) | b1 (32) | W2 (32)

    const int tid  = threadIdx.x;
    const int wave = tid >> 6;
    const int lane = tid & 63;
    const int g    = lane >> 4;   // K-group: this lane's frequency band
    const int c    = lane & 15;   // col-within-16 (point low bits / j-row)

    // ---- cooperative weight stage: one coalesced float4 per thread ----
    if (tid < 232) {
        float4 v;
        if (tid < 216)      v = ((const float4*)W1)[tid];
        else if (tid < 224) v = ((const float4*)b1)[tid - 216];
        else                v = ((const float4*)W2)[tid - 224];
        ((float4*)ws)[tid] = v;
    }

    // ---- packed sincos table (overlaps with the staging load latency) ----
    #pragma unroll
    for (int i = 0; i < TABN / BLOCK; ++i) {
        const int idx = tid + i * BLOCK;
        const float a = (float)idx * (1.0f / TABN);   // revolutions
        f32x2 sc;
        sc[0] = __builtin_amdgcn_sinf(a);
        sc[1] = __builtin_amdgcn_cosf(a);
        stab[idx] = __builtin_bit_cast(u32, __builtin_convertvector(sc, bf16x2));
    }

    const float INV2PI = 0.15915494309189535f;
    float Fg = 1.0f;
    Fg = (g == 1) ? 10.079368f : Fg;
    Fg = (g == 2) ? 101.59367f : Fg;
    Fg = (g == 3) ? 1024.0f    : Fg;
    const float FgN = Fg * INV2PI * (float)TABN;   // x -> table-index scale

    const float bias2 = b2[0];
    const f32x4 Z = {0.f, 0.f, 0.f, 0.f};

    __syncthreads();

    // ---- per-lane fragments from LDS (interleaved k-order) ----
    // k-slot: 2m = sin_g(x_m) row 3+6g+m; 2m+1 = cos_g(x_m) row 6+6g+m;
    //         6 = extra (row g | bias); 7 = 0.
    bf16x8 afrag[2];
    #pragma unroll
    for (int mt = 0; mt < 2; ++mt) {
        const int j = mt * 16 + c;
        f32x8 af;
        #pragma unroll
        for (int m = 0; m < 3; ++m) {
            af[2 * m]     = ws[(3 + 6 * g + m) * 32 + j];
            af[2 * m + 1] = ws[(6 + 6 * g + m) * 32 + j];
        }
        af[6] = (g < 3) ? ws[g * 32 + j] : ws[864 + j];
        af[7] = 0.0f;
        afrag[mt] = __builtin_convertvector(af, bf16x8);
    }
    bf16x8 a2;
    {
        f32x8 a2f;
        #pragma unroll
        for (int i = 0; i < 4; ++i) {
            a2f[i]     = ws[896 + 4 * g + i];
            a2f[4 + i] = ws[896 + 16 + 4 * g + i];
        }
        a2 = __builtin_convertvector(a2f, bf16x8);
    }

    const int tbase = blockIdx.x * (4 * TILES) + wave * TILES;

    #pragma unroll
    for (int t = 0; t < TILES; ++t) {
        const float3* xb3 = (const float3*)(x + (size_t)(tbase + t) * 192);
        float3 P[4];
        #pragma unroll
        for (int nt = 0; nt < 4; ++nt) P[nt] = xb3[16 * nt + c];

        float p[4];
        #pragma unroll
        for (int nt = 0; nt < 4; ++nt) {
            const float x0 = P[nt].x, x1 = P[nt].y, x2 = P[nt].z;

            // one packed {sin,cos} read per component; &4095 wraps the phase
            const int i0 = (int)(x0 * FgN);
            const int i1 = (int)(x1 * FgN);
            const int i2 = (int)(x2 * FgN);
            float extra = x0;
            extra = (g == 1) ? x1 : extra;
            extra = (g == 2) ? x2 : extra;
            extra = (g == 3) ? 1.0f : extra;

            u32x4 uu;
            uu[0] = stab[i0 & (TABN - 1)];
            uu[1] = stab[i1 & (TABN - 1)];
            uu[2] = stab[i2 & (TABN - 1)];
            f32x2 ex = {extra, 0.0f};
            uu[3] = __builtin_bit_cast(u32, __builtin_convertvector(ex, bf16x2));
            const bf16x8 bf = __builtin_bit_cast(bf16x8, uu);

            // layer 1: 2 MFMAs -> lane holds h[4g+r] (acc0), h[16+4g+r] (acc1)
            const f32x4 acc0 =
                __builtin_amdgcn_mfma_f32_16x16x32_bf16(afrag[0], bf, Z, 0, 0, 0);
            const f32x4 acc1 =
                __builtin_amdgcn_mfma_f32_16x16x32_bf16(afrag[1], bf, Z, 0, 0, 0);

            // layer 2: relu -> bf16 -> one MFMA; answer in o[0]
            f32x8 hf;
            #pragma unroll
            for (int r = 0; r < 4; ++r) {
                hf[r]     = fmaxf(acc0[r], 0.0f);
                hf[4 + r] = fmaxf(acc1[r], 0.0f);
            }
            const bf16x8 h8 = __builtin_convertvector(hf, bf16x8);
            const f32x4 o =
                __builtin_amdgcn_mfma_f32_16x16x32_bf16(a2, h8, Z, 0, 0, 0);
            p[nt] = o[0];
        }

        float v = p[0];
        v = (g == 1) ? p[1] : v;
        v = (g == 2) ? p[2] : v;
        v = (g == 3) ? p[3] : v;
        out[(size_t)(tbase + t) * 64 + lane] = fmaxf(v + bias2, 0.0f);
    }
}

extern "C" void kernel_launch(void* const* d_in, const int* in_sizes, int n_in,
                              void* d_out, int out_size, void* d_ws, size_t ws_size,
                              hipStream_t stream) {
    const float* x  = (const float*)d_in[0];
    const float* W1 = (const float*)d_in[1];
    const float* b1 = (const float*)d_in[2];
    const float* W2 = (const float*)d_in[3];
    const float* b2 = (const float*)d_in[4];
    float* out = (float*)d_out;

    nerf_ptab<<<NBLK, BLOCK, 0, stream>>>(x, W1, b1, W2, b2, out);
}

// Round 13
// 18.144 us; speedup vs baseline: 1.1868x; 1.1011x over previous
//
#include <hip/hip_runtime.h>

// Fused NeRF: PE (4 freq) + MLP 27->32->1, both layers bf16 MFMA.
// R12 "instruction diet": byte-scaled LDS table offsets (no shifts),
// single-base imm-offset loads/stores, f32x2 relu (v_pk_max), BLOCK=512
// (1024 workgroups -> half the dispatch ramp; same 8192 waves, 8/SIMD).

#define NPTS  2097152
#define BLOCK 512
#define TILES 4
#define NBLK  (NPTS / (BLOCK * TILES))   // 1024
#define TABN  4096

typedef __bf16 bf16x8 __attribute__((ext_vector_type(8)));
typedef __bf16 bf16x2 __attribute__((ext_vector_type(2)));
typedef float  f32x8  __attribute__((ext_vector_type(8)));
typedef float  f32x4  __attribute__((ext_vector_type(4)));
typedef float  f32x2  __attribute__((ext_vector_type(2)));
typedef unsigned int u32;
typedef u32 u32x4 __attribute__((ext_vector_type(4)));

__global__ __launch_bounds__(BLOCK, 4) void nerf_diet(
    const float* __restrict__ x,
    const float* __restrict__ W1,
    const float* __restrict__ b1,
    const float* __restrict__ W2,
    const float* __restrict__ b2,
    float* __restrict__ out)
{
    __shared__ u32 stab[TABN];                 // {bf16 sin | bf16 cos<<16}
    __shared__ __align__(16) float ws[928];    // W1 (864) | b1 (32) | W2 (32)

    const int tid  = threadIdx.x;
    const int wave = tid >> 6;
    const int lane = tid & 63;
    const int g    = lane >> 4;   // K-group: lane's frequency band
    const int c    = lane & 15;   // col-within-16 (point low bits / j-row)

    // ---- cooperative weight stage: one coalesced float4 per thread ----
    if (tid < 232) {
        float4 v;
        if (tid < 216)      v = ((const float4*)W1)[tid];
        else if (tid < 224) v = ((const float4*)b1)[tid - 216];
        else                v = ((const float4*)W2)[tid - 224];
        ((float4*)ws)[tid] = v;
    }

    // ---- packed sincos table ----
    #pragma unroll
    for (int i = 0; i < TABN / BLOCK; ++i) {
        const int idx = tid + i * BLOCK;
        const float a = (float)idx * (1.0f / TABN);   // revolutions
        f32x2 sc;
        sc[0] = __builtin_amdgcn_sinf(a);
        sc[1] = __builtin_amdgcn_cosf(a);
        stab[idx] = __builtin_bit_cast(u32, __builtin_convertvector(sc, bf16x2));
    }

    const float INV2PI = 0.15915494309189535f;
    float Fg = 1.0f;
    Fg = (g == 1) ? 10.079368f : Fg;
    Fg = (g == 2) ? 101.59367f : Fg;
    Fg = (g == 3) ? 1024.0f    : Fg;
    // x -> BYTE offset into stab (index<<2 pre-folded; mask keeps alignment)
    const float FgN4 = Fg * INV2PI * (float)TABN * 4.0f;

    const float bias2 = b2[0];
    const f32x4 Z = {0.f, 0.f, 0.f, 0.f};

    __syncthreads();

    // ---- per-lane fragments from LDS (interleaved k-order) ----
    bf16x8 afrag[2];
    #pragma unroll
    for (int mt = 0; mt < 2; ++mt) {
        const int j = mt * 16 + c;
        f32x8 af;
        #pragma unroll
        for (int m = 0; m < 3; ++m) {
            af[2 * m]     = ws[(3 + 6 * g + m) * 32 + j];   // sin_g(x_m) row
            af[2 * m + 1] = ws[(6 + 6 * g + m) * 32 + j];   // cos_g(x_m) row
        }
        af[6] = (g < 3) ? ws[g * 32 + j] : ws[864 + j];     // linear | bias
        af[7] = 0.0f;
        afrag[mt] = __builtin_convertvector(af, bf16x8);
    }
    bf16x8 a2;
    {
        f32x8 a2f;
        #pragma unroll
        for (int i = 0; i < 4; ++i) {
            a2f[i]     = ws[896 + 4 * g + i];
            a2f[4 + i] = ws[896 + 16 + 4 * g + i];
        }
        a2 = __builtin_convertvector(a2f, bf16x8);
    }

    const char* stabB = (const char*)stab;
    const int tbase = blockIdx.x * ((BLOCK / 64) * TILES) + wave * TILES;
    // single bases; all tile/nt offsets are compile-time -> imm "offset:"
    const float* xb = x + (size_t)tbase * 192 + c * 3;
    float* ob = out + (size_t)tbase * 64 + lane;

    #pragma unroll
    for (int t = 0; t < TILES; ++t) {
        float p[4];
        #pragma unroll
        for (int nt = 0; nt < 4; ++nt) {
            // point (16nt+c): 3 floats at constant offset from xb
            const float x0 = xb[t * 192 + nt * 48 + 0];
            const float x1 = xb[t * 192 + nt * 48 + 1];
            const float x2 = xb[t * 192 + nt * 48 + 2];

            // byte-offset table lookups (mul+cvt+and+ds_read, no shift)
            const u32 o0 = (u32)(int)(x0 * FgN4) & (4 * (TABN - 1));
            const u32 o1 = (u32)(int)(x1 * FgN4) & (4 * (TABN - 1));
            const u32 o2 = (u32)(int)(x2 * FgN4) & (4 * (TABN - 1));

            float extra = x0;
            extra = (g == 1) ? x1 : extra;
            extra = (g == 2) ? x2 : extra;
            extra = (g == 3) ? 1.0f : extra;

            u32x4 uu;
            uu[0] = *(const u32*)(stabB + o0);
            uu[1] = *(const u32*)(stabB + o1);
            uu[2] = *(const u32*)(stabB + o2);
            f32x2 ex = {extra, 0.0f};
            uu[3] = __builtin_bit_cast(u32, __builtin_convertvector(ex, bf16x2));
            const bf16x8 bf = __builtin_bit_cast(bf16x8, uu);

            // layer 1: 2 MFMAs -> lane holds h[4g+r], h[16+4g+r]
            const f32x4 acc0 =
                __builtin_amdgcn_mfma_f32_16x16x32_bf16(afrag[0], bf, Z, 0, 0, 0);
            const f32x4 acc1 =
                __builtin_amdgcn_mfma_f32_16x16x32_bf16(afrag[1], bf, Z, 0, 0, 0);

            // relu shaped as f32x2 ops (v_pk_max candidates), then pack
            f32x8 hf;
            #pragma unroll
            for (int rr = 0; rr < 2; ++rr) {
                f32x2 lo = {acc0[2 * rr], acc0[2 * rr + 1]};
                f32x2 hi = {acc1[2 * rr], acc1[2 * rr + 1]};
                f32x2 zz = {0.f, 0.f};
                lo = __builtin_elementwise_max(lo, zz);
                hi = __builtin_elementwise_max(hi, zz);
                hf[2 * rr] = lo[0]; hf[2 * rr + 1] = lo[1];
                hf[4 + 2 * rr] = hi[0]; hf[4 + 2 * rr + 1] = hi[1];
            }
            const bf16x8 h8 = __builtin_convertvector(hf, bf16x8);
            const f32x4 o =
                __builtin_amdgcn_mfma_f32_16x16x32_bf16(a2, h8, Z, 0, 0, 0);
            p[nt] = o[0];
        }

        float v = p[0];
        v = (g == 1) ? p[1] : v;
        v = (g == 2) ? p[2] : v;
        v = (g == 3) ? p[3] : v;
        ob[t * 64] = fmaxf(v + bias2, 0.0f);
    }
}

extern "C" void kernel_launch(void* const* d_in, const int* in_sizes, int n_in,
                              void* d_out, int out_size, void* d_ws, size_t ws_size,
                              hipStream_t stream) {
    const float* x  = (const float*)d_in[0];
    const float* W1 = (const float*)d_in[1];
    const float* b1 = (const float*)d_in[2];
    const float* W2 = (const float*)d_in[3];
    const float* b2 = (const float*)d_in[4];
    float* out = (float*)d_out;

    nerf_diet<<<NBLK, BLOCK, 0, stream>>>(x, W1, b1, W2, b2, out);
}

// Round 14
// 17.986 us; speedup vs baseline: 1.1973x; 1.0088x over previous
//
#include <hip/hip_runtime.h>

// Fused NeRF: PE (4 freq) + MLP 27->32->1 via 32x32x16 bf16 MFMA (K=28->2x16).
// Lane (h=lane>>5, col=lane&31) owns point 32gr+col at bands {h, 2+h}.
// Packed bf16 {sin,cos} LDS table feeds B-fragments directly (no cvt_pk).
// K order (W1 rows permuted identically for A and B -> mapping cancels):
//  MFMA1 k=8h+i: i=2m sin_h(x_m) row 3+6h+m; i=2m+1 cos_h(x_m) row 6+6h+m;
//                i=6: h?x2:x0 (row 2|0); i=7: h?bias:x1 (b1|row 1).
//  MFMA2 k=8h+i: i=2m sin_{2+h} row 15+6h+m; i=2m+1 cos_{2+h} row 18+6h+m; 0,0.
// C/D (verified R5/m74): col=lane&31, row=(reg&3)+8*(reg>>2)+4h.

#define NPTS  2097152
#define BLOCK 512
#define TILES 4
#define NBLK  (NPTS / (64 * (BLOCK / 64) * TILES))   // 1024
#define TABN  4096

typedef __bf16 bf16x8 __attribute__((ext_vector_type(8)));
typedef __bf16 bf16x2 __attribute__((ext_vector_type(2)));
typedef float  f32x8  __attribute__((ext_vector_type(8)));
typedef float  f32x16 __attribute__((ext_vector_type(16)));
typedef float  f32x2  __attribute__((ext_vector_type(2)));
typedef unsigned int u32;
typedef u32 u32x4 __attribute__((ext_vector_type(4)));

__global__ __launch_bounds__(BLOCK, 4) void nerf_32x32(
    const float* __restrict__ x,
    const float* __restrict__ W1,
    const float* __restrict__ b1,
    const float* __restrict__ W2,
    const float* __restrict__ b2,
    float* __restrict__ out)
{
    __shared__ u32 stab[TABN];                 // {bf16 sin | bf16 cos<<16}
    __shared__ __align__(16) float ws[928];    // W1 (864) | b1 (32) | W2 (32)

    const int tid  = threadIdx.x;
    const int wave = tid >> 6;
    const int lane = tid & 63;
    const int h    = lane >> 5;   // k-half: bands {h, 2+h}
    const int col  = lane & 31;   // point-in-group / hidden j (A operand)

    // ---- cooperative weight stage (coalesced float4) ----
    if (tid < 232) {
        float4 v;
        if (tid < 216)      v = ((const float4*)W1)[tid];
        else if (tid < 224) v = ((const float4*)b1)[tid - 216];
        else                v = ((const float4*)W2)[tid - 224];
        ((float4*)ws)[tid] = v;
    }
    // ---- packed sincos table ----
    #pragma unroll
    for (int i = 0; i < TABN / BLOCK; ++i) {
        const int idx = tid + i * BLOCK;
        const float a = (float)idx * (1.0f / TABN);
        f32x2 sc;
        sc[0] = __builtin_amdgcn_sinf(a);
        sc[1] = __builtin_amdgcn_cosf(a);
        stab[idx] = __builtin_bit_cast(u32, __builtin_convertvector(sc, bf16x2));
    }

    // per-lane band scales -> BYTE offset into stab
    const float C4 = 0.15915494309189535f * (float)TABN * 4.0f;
    const float FgA = (h ? 10.0793684f : 1.0f)        * C4;
    const float FgB = (h ? 1024.0f     : 101.5936673f) * C4;
    const float bias2 = b2[0];
    const f32x16 Z = {};

    __syncthreads();

    // ---- layer-1 A fragments from LDS (k-order above), j = col ----
    bf16x8 af1, af2;
    {
        f32x8 t1, t2;
        #pragma unroll
        for (int m = 0; m < 3; ++m) {
            t1[2 * m]     = ws[(3  + 6 * h + m) * 32 + col];
            t1[2 * m + 1] = ws[(6  + 6 * h + m) * 32 + col];
            t2[2 * m]     = ws[(15 + 6 * h + m) * 32 + col];
            t2[2 * m + 1] = ws[(18 + 6 * h + m) * 32 + col];
        }
        t1[6] = h ? ws[2 * 32 + col] : ws[0 * 32 + col];
        t1[7] = h ? ws[864 + col]    : ws[1 * 32 + col];   // bias | x1-row
        t2[6] = 0.0f; t2[7] = 0.0f;
        af1 = __builtin_convertvector(t1, bf16x8);
        af2 = __builtin_convertvector(t2, bf16x8);
    }
    // layer-2 weights for lane's 16 C/D rows (pairs for pk_fma)
    f32x2 w2p[8];
    #pragma unroll
    for (int m = 0; m < 8; ++m) {
        const int r0 = 896 + 8 * (m >> 1) + 4 * h + 2 * (m & 1);
        w2p[m][0] = ws[r0];
        w2p[m][1] = ws[r0 + 1];
    }

    const char* stabB = (const char*)stab;
    const int tbase = blockIdx.x * ((BLOCK / 64) * TILES) + wave * TILES;
    const float* xb = x + (size_t)tbase * 192 + col * 3;   // my col's base
    float* ob = out + (size_t)tbase * 64 + lane;

    #pragma unroll
    for (int t = 0; t < TILES; ++t) {
        float S[2];
        #pragma unroll
        for (int gr = 0; gr < 2; ++gr) {
            // my point for this group: 64t + 32gr + col (imm offsets)
            const float x0 = xb[t * 192 + gr * 96 + 0];
            const float x1 = xb[t * 192 + gr * 96 + 1];
            const float x2 = xb[t * 192 + gr * 96 + 2];

            // 6 packed {sin,cos} lookups: bands h (A) and 2+h (B)
            const u32 mA0 = (u32)(int)(x0 * FgA) & (4 * (TABN - 1));
            const u32 mA1 = (u32)(int)(x1 * FgA) & (4 * (TABN - 1));
            const u32 mA2 = (u32)(int)(x2 * FgA) & (4 * (TABN - 1));
            const u32 mB0 = (u32)(int)(x0 * FgB) & (4 * (TABN - 1));
            const u32 mB1 = (u32)(int)(x1 * FgB) & (4 * (TABN - 1));
            const u32 mB2 = (u32)(int)(x2 * FgB) & (4 * (TABN - 1));

            u32x4 u1, u2;
            u1[0] = *(const u32*)(stabB + mA0);
            u1[1] = *(const u32*)(stabB + mA1);
            u1[2] = *(const u32*)(stabB + mA2);
            f32x2 ex;
            ex[0] = h ? x2 : x0;
            ex[1] = h ? 1.0f : x1;     // bias multiplier lives in h=1
            u1[3] = __builtin_bit_cast(u32, __builtin_convertvector(ex, bf16x2));
            u2[0] = *(const u32*)(stabB + mB0);
            u2[1] = *(const u32*)(stabB + mB1);
            u2[2] = *(const u32*)(stabB + mB2);
            u2[3] = 0u;
            const bf16x8 B1 = __builtin_bit_cast(bf16x8, u1);
            const bf16x8 B2 = __builtin_bit_cast(bf16x8, u2);

            // layer 1: 2 chained 32x32x16 MFMAs -> 32 hidden x 32 points
            f32x16 acc = __builtin_amdgcn_mfma_f32_32x32x16_bf16(af1, B1, Z, 0, 0, 0);
            acc = __builtin_amdgcn_mfma_f32_32x32x16_bf16(af2, B2, acc, 0, 0, 0);

            // layer 2: relu + pk_fma over lane's 16 rows, fold halves
            f32x2 ps = {0.0f, 0.0f};
            #pragma unroll
            for (int m = 0; m < 8; ++m) {
                f32x2 v = {acc[2 * m], acc[2 * m + 1]};
                f32x2 zz = {0.f, 0.f};
                v = __builtin_elementwise_max(v, zz);
                ps = ps + v * w2p[m];
            }
            float s = ps[0] + ps[1];
            s += __shfl_xor(s, 32, 64);   // combine k-halves (rows +4h)
            S[gr] = s;
        }
        // lane (h,col) stores point 32h+col of the tile
        const float v = h ? S[1] : S[0];
        ob[t * 64] = fmaxf(v + bias2, 0.0f);
    }
}

extern "C" void kernel_launch(void* const* d_in, const int* in_sizes, int n_in,
                              void* d_out, int out_size, void* d_ws, size_t ws_size,
                              hipStream_t stream) {
    const float* x  = (const float*)d_in[0];
    const float* W1 = (const float*)d_in[1];
    const float* b1 = (const float*)d_in[2];
    const float* W2 = (const float*)d_in[3];
    const float* b2 = (const float*)d_in[4];
    float* out = (float*)d_out;

    nerf_32x32<<<NBLK, BLOCK, 0, stream>>>(x, W1, b1, W2, b2, out);
}